// Round 6
// baseline (409.234 us; speedup 1.0000x reference)
//
#include <hip/hip_runtime.h>
#include <stdint.h>

// Problem constants
#define T_TOK 4096   // B*S
#define DIM   512    // D
#define NEXP  16     // E
#define DHID  2048   // 4*D
#define DSH   1024   // 2*D
#define ROWSCAP 10240  // 2*T + padding slack
#define MAXTILES 80    // sum ceil(c_e/128) <= 79

typedef __bf16 bf16x8 __attribute__((ext_vector_type(8)));
typedef float  f32x4  __attribute__((ext_vector_type(4)));
typedef unsigned short usv8 __attribute__((ext_vector_type(8)));

__device__ __forceinline__ unsigned short f2b(float f) {
  union { float f; unsigned int u; } un; un.f = f;
  unsigned int u = un.u + 0x7fffu + ((un.u >> 16) & 1u);  // RNE to bf16
  return (unsigned short)(u >> 16);
}
__device__ __forceinline__ float b2f(unsigned short u) {
  union { unsigned int u; float f; } un; un.u = ((unsigned int)u) << 16; return un.f;
}

__device__ __forceinline__ void async16(void* lds, const void* gp) {
  __builtin_amdgcn_global_load_lds(
      (const __attribute__((address_space(1))) unsigned int*)gp,
      (__attribute__((address_space(3))) unsigned int*)lds, 16, 0, 0);
}

// ---------------- 64x64 transpose tile: fp32 [R,C] -> bf16 [C,R] ----------------
// LDS: float row-major [64][65] (65 = 1 mod 32 -> all scalar accesses 2-way = free).
__device__ __forceinline__ void transpose64(
    const float* __restrict__ s, unsigned short* __restrict__ d, int R, int C,
    int tx, int ty, float* tile) {
  const int tid = threadIdx.x;
  const int c0 = tx * 64, r0 = ty * 64;
  const int r = tid >> 4, j4 = (tid & 15) * 4;
#pragma unroll
  for (int p = 0; p < 4; ++p) {
    const int row = r + p * 16;
    const float4 v = *(const float4*)&s[(size_t)(r0 + row) * C + c0 + j4];
    tile[row * 65 + j4 + 0] = v.x;
    tile[row * 65 + j4 + 1] = v.y;
    tile[row * 65 + j4 + 2] = v.z;
    tile[row * 65 + j4 + 3] = v.w;
  }
  __syncthreads();
  const int jj = tid & 7, cc = tid >> 3;
#pragma unroll
  for (int p = 0; p < 2; ++p) {
    const int c = cc + p * 32;
    usv8 u;
#pragma unroll
    for (int i = 0; i < 8; ++i) u[i] = f2b(tile[(jj * 8 + i) * 65 + c]);
    *(usv8*)&d[(size_t)(c0 + c) * R + r0 + jj * 8] = u;
  }
}

// ---------------- prep: all weight transposes + LN+router+top2, one dispatch ----------------
__global__ __launch_bounds__(256) void prep_kernel(
    const float* __restrict__ x, const float* __restrict__ g, const float* __restrict__ b,
    const float* __restrict__ rw, const float* __restrict__ rb,
    unsigned short* __restrict__ hbuf, int* __restrict__ comb_idx, float* __restrict__ comb_w,
    int* __restrict__ counts,
    const float* __restrict__ ew1, const float* __restrict__ ew2,
    const float* __restrict__ sw1, const float* __restrict__ sw2,
    const float* __restrict__ fw1, const float* __restrict__ fw2,
    unsigned short* __restrict__ ew1T, unsigned short* __restrict__ ew2T,
    unsigned short* __restrict__ sw1T, unsigned short* __restrict__ sw2T,
    unsigned short* __restrict__ fw1T, unsigned short* __restrict__ fw2T) {
  __shared__ float tile[64 * 65];
  __shared__ int hist[NEXP];
  const int id = blockIdx.x;
  if (id >= 1024) {
    int id2 = id - 1024;
    const float* s; unsigned short* d; int R, C, t, tx, ty;
    if (id2 < 4096)      { int bm = id2 >> 8; t = id2 & 255; R = 512;  C = 2048;
                           s = ew1 + (size_t)bm * R * C; d = ew1T + (size_t)bm * R * C;
                           tx = t & 31; ty = t >> 5; }
    else if (id2 < 8192) { id2 -= 4096; int bm = id2 >> 8; t = id2 & 255; R = 2048; C = 512;
                           s = ew2 + (size_t)bm * R * C; d = ew2T + (size_t)bm * R * C;
                           tx = t & 7;  ty = t >> 3; }
    else if (id2 < 8320) { t = id2 - 8192; R = 512;  C = 1024; s = sw1; d = sw1T; tx = t & 15; ty = t >> 4; }
    else if (id2 < 8448) { t = id2 - 8320; R = 1024; C = 512;  s = sw2; d = sw2T; tx = t & 7;  ty = t >> 3; }
    else if (id2 < 8704) { t = id2 - 8448; R = 512;  C = 2048; s = fw1; d = fw1T; tx = t & 31; ty = t >> 5; }
    else                 { t = id2 - 8704; R = 2048; C = 512;  s = fw2; d = fw2T; tx = t & 7;  ty = t >> 3; }
    transpose64(s, d, R, C, tx, ty, tile);
    return;
  }
  // ---- LN + router path (wave-per-token) ----
  const int wid = threadIdx.x >> 6, lane = threadIdx.x & 63;
  const int t = id * 4 + wid;
  if (threadIdx.x < NEXP) hist[threadIdx.x] = 0;
  __syncthreads();

  const float4* xr = (const float4*)(x + (size_t)t * DIM);
  const float4 va = xr[lane], vb = xr[lane + 64];
  float s = (va.x + va.y) + (va.z + va.w) + ((vb.x + vb.y) + (vb.z + vb.w));
#pragma unroll
  for (int o = 32; o; o >>= 1) s += __shfl_xor(s, o, 64);
  const float mu = s * (1.f / DIM);
  float da[4] = {va.x - mu, va.y - mu, va.z - mu, va.w - mu};
  float db[4] = {vb.x - mu, vb.y - mu, vb.z - mu, vb.w - mu};
  float q = (da[0]*da[0] + da[1]*da[1]) + (da[2]*da[2] + da[3]*da[3]) +
            ((db[0]*db[0] + db[1]*db[1]) + (db[2]*db[2] + db[3]*db[3]));
#pragma unroll
  for (int o = 32; o; o >>= 1) q += __shfl_xor(q, o, 64);
  const float rs = rsqrtf(q * (1.f / DIM) + 1e-5f);
  const float4 ga = ((const float4*)g)[lane], gb4 = ((const float4*)g)[lane + 64];
  const float4 ba = ((const float4*)b)[lane], bb4 = ((const float4*)b)[lane + 64];
  float ha[4], hbv[4];
  ha[0] = da[0] * rs * ga.x + ba.x;  ha[1] = da[1] * rs * ga.y + ba.y;
  ha[2] = da[2] * rs * ga.z + ba.z;  ha[3] = da[3] * rs * ga.w + ba.w;
  hbv[0] = db[0] * rs * gb4.x + bb4.x;  hbv[1] = db[1] * rs * gb4.y + bb4.y;
  hbv[2] = db[2] * rs * gb4.z + bb4.z;  hbv[3] = db[3] * rs * gb4.w + bb4.w;
  ushort4 ua = {f2b(ha[0]), f2b(ha[1]), f2b(ha[2]), f2b(ha[3])};
  ushort4 ub = {f2b(hbv[0]), f2b(hbv[1]), f2b(hbv[2]), f2b(hbv[3])};
  ((ushort4*)(hbuf + (size_t)t * DIM))[lane] = ua;
  ((ushort4*)(hbuf + (size_t)t * DIM))[lane + 64] = ub;

  float p[NEXP];
#pragma unroll
  for (int e = 0; e < NEXP; ++e) p[e] = 0.f;
  const int col0 = lane * 4;
#pragma unroll
  for (int half = 0; half < 2; ++half) {
#pragma unroll
    for (int j = 0; j < 4; ++j) {
      const int col = half * 256 + col0 + j;
      const float hv = half ? hbv[j] : ha[j];
      const float4* wr = (const float4*)(rw + (size_t)col * NEXP);
#pragma unroll
      for (int qq = 0; qq < 4; ++qq) {
        const float4 w = wr[qq];
        p[qq * 4 + 0] += hv * w.x;  p[qq * 4 + 1] += hv * w.y;
        p[qq * 4 + 2] += hv * w.z;  p[qq * 4 + 3] += hv * w.w;
      }
    }
  }
#pragma unroll
  for (int o = 32; o; o >>= 1) {
#pragma unroll
    for (int e = 0; e < NEXP; ++e) p[e] += __shfl_xor(p[e], o, 64);
  }
  float mx = -1e30f;
#pragma unroll
  for (int e = 0; e < NEXP; ++e) {
    p[e] = (p[e] + rb[e]) * (1.f / 0.7f);
    mx = fmaxf(mx, p[e]);
  }
  float ge[NEXP], se = 0.f;
#pragma unroll
  for (int e = 0; e < NEXP; ++e) { ge[e] = __expf(p[e] - mx); se += ge[e]; }
  const float inv = 1.f / se;
  int i0 = 0; float m0 = ge[0];
#pragma unroll
  for (int e = 1; e < NEXP; ++e) if (ge[e] > m0) { m0 = ge[e]; i0 = e; }
  int i1 = -1; float m1 = -1.f;
#pragma unroll
  for (int e = 0; e < NEXP; ++e) if (e != i0 && ge[e] > m1) { m1 = ge[e]; i1 = e; }
  if (lane == 0) {
    comb_idx[t * 2] = i0; comb_idx[t * 2 + 1] = i1;
    comb_w[t * 2] = m0 * inv; comb_w[t * 2 + 1] = m1 * inv;
    atomicAdd(&hist[i0], 1); atomicAdd(&hist[i1], 1);
  }
  __syncthreads();
  if (threadIdx.x < NEXP) {
    const int c = hist[threadIdx.x];
    if (c) atomicAdd(&counts[threadIdx.x], c);
  }
}

// ---------------- plan: padded segment offsets + tile descriptors ----------------
__global__ void plan_kernel(const int* __restrict__ counts, int* __restrict__ offs,
                            int* __restrict__ fill, int* __restrict__ tiledesc) {
  if (threadIdx.x == 0) {
    int run = 0, tix = 0;
    for (int e = 0; e < NEXP; ++e) {
      offs[e] = run;
      const int nt = (counts[e] + 127) >> 7;
      for (int i = 0; i < nt; ++i) { tiledesc[tix * 2] = e; tiledesc[tix * 2 + 1] = run + i * 128; ++tix; }
      run += nt * 128;
    }
    for (; tix < MAXTILES; ++tix) { tiledesc[tix * 2] = -1; tiledesc[tix * 2 + 1] = 0; }
  }
  if (threadIdx.x < NEXP) fill[threadIdx.x] = 0;
}

// ---------------- scatter tokens into expert segments (records slots) ----------------
__global__ __launch_bounds__(256) void scatter_kernel(
    const int* __restrict__ comb_idx, const float* __restrict__ comb_w,
    const int* __restrict__ offs, int* __restrict__ fill,
    int* __restrict__ token_list, int* __restrict__ slots) {
  const int t = blockIdx.x * 256 + threadIdx.x;
#pragma unroll
  for (int j = 0; j < 2; ++j) {
    const int e = comb_idx[t * 2 + j];
    const int p = atomicAdd(&fill[e], 1);
    const int gidx = offs[e] + p;
    token_list[gidx] = t;
    slots[t * 2 + j] = gidx;
  }
}

// ---------------- combine + LayerNorm ----------------
__global__ __launch_bounds__(256) void combine_ln_kernel(
    const unsigned short* __restrict__ eyb, const float* __restrict__ shb,
    const int* __restrict__ slots, const float* __restrict__ comb_w,
    const float* __restrict__ g, const float* __restrict__ b,
    float* __restrict__ moe, unsigned short* __restrict__ fhb) {
  const int wid = threadIdx.x >> 6, lane = threadIdx.x & 63;
  const int t = blockIdx.x * 4 + wid;
  const int s0 = slots[t * 2], s1 = slots[t * 2 + 1];
  const float w0 = comb_w[t * 2], w1 = comb_w[t * 2 + 1];
  const uint4 E0 = ((const uint4*)(eyb + (size_t)s0 * DIM))[lane];
  const uint4 E1 = ((const uint4*)(eyb + (size_t)s1 * DIM))[lane];
  const float4 sa = ((const float4*)(shb + (size_t)t * DIM))[lane * 2];
  const float4 sb = ((const float4*)(shb + (size_t)t * DIM))[lane * 2 + 1];
  const unsigned int e0[4] = {E0.x, E0.y, E0.z, E0.w};
  const unsigned int e1[4] = {E1.x, E1.y, E1.z, E1.w};
  const float shv[8] = {sa.x, sa.y, sa.z, sa.w, sb.x, sb.y, sb.z, sb.w};
  float m[8];
#pragma unroll
  for (int j = 0; j < 4; ++j) {
    m[2*j]   = w0 * b2f((unsigned short)(e0[j] & 0xffff)) + w1 * b2f((unsigned short)(e1[j] & 0xffff)) + shv[2*j];
    m[2*j+1] = w0 * b2f((unsigned short)(e0[j] >> 16))    + w1 * b2f((unsigned short)(e1[j] >> 16))    + shv[2*j+1];
  }
  float4* mo = (float4*)(moe + (size_t)t * DIM);
  mo[lane * 2]     = make_float4(m[0], m[1], m[2], m[3]);
  mo[lane * 2 + 1] = make_float4(m[4], m[5], m[6], m[7]);
  float s = 0.f;
#pragma unroll
  for (int j = 0; j < 8; ++j) s += m[j];
#pragma unroll
  for (int o = 32; o; o >>= 1) s += __shfl_xor(s, o, 64);
  const float mu = s * (1.f / DIM);
  float q = 0.f;
#pragma unroll
  for (int j = 0; j < 8; ++j) { const float d = m[j] - mu; q += d * d; }
#pragma unroll
  for (int o = 32; o; o >>= 1) q += __shfl_xor(q, o, 64);
  const float rs = rsqrtf(q * (1.f / DIM) + 1e-5f);
  const float4 ga = ((const float4*)g)[lane * 2], gb4 = ((const float4*)g)[lane * 2 + 1];
  const float4 ba = ((const float4*)b)[lane * 2], bb4 = ((const float4*)b)[lane * 2 + 1];
  const float gv[8] = {ga.x, ga.y, ga.z, ga.w, gb4.x, gb4.y, gb4.z, gb4.w};
  const float bv[8] = {ba.x, ba.y, ba.z, ba.w, bb4.x, bb4.y, bb4.z, bb4.w};
  ushort4 o0, o1;
  o0.x = f2b((m[0]-mu)*rs*gv[0]+bv[0]); o0.y = f2b((m[1]-mu)*rs*gv[1]+bv[1]);
  o0.z = f2b((m[2]-mu)*rs*gv[2]+bv[2]); o0.w = f2b((m[3]-mu)*rs*gv[3]+bv[3]);
  o1.x = f2b((m[4]-mu)*rs*gv[4]+bv[4]); o1.y = f2b((m[5]-mu)*rs*gv[5]+bv[5]);
  o1.z = f2b((m[6]-mu)*rs*gv[6]+bv[6]); o1.w = f2b((m[7]-mu)*rs*gv[7]+bv[7]);
  ((ushort4*)(fhb + (size_t)t * DIM))[lane * 2]     = o0;
  ((ushort4*)(fhb + (size_t)t * DIM))[lane * 2 + 1] = o1;
}

// ---------------- bf16 MFMA GEMM body, BMx128x64 step (BK=64: 32 MFMA / barrier) ----------------
// MODE 0: outA = silu(acc+bias) bf16 | MODE 1: outA = acc+bias bf16
// MODE 2: outp = 0.25*(acc+bias) fp32 | MODE 3: outp = xres + mix + (acc+bias)
template <int MODE, bool EXPERT, int BM>
__device__ __forceinline__ void gemm_body(
    const unsigned short* __restrict__ A, int lda,
    const unsigned short* __restrict__ BT, const float* __restrict__ bias,
    int K, int N, int row0, int expert, int bn,
    const int* __restrict__ token_list,
    unsigned short* __restrict__ outA, const float* __restrict__ mix,
    const float* __restrict__ xres, float* __restrict__ outp,
    unsigned short* As, unsigned short* Bs) {
  const int tid = threadIdx.x;
  const unsigned short* Bt = BT + (size_t)expert * N * K + (size_t)bn * 128 * K;
  const float* bp = bias + (EXPERT ? expert * N : 0) + bn * 128;

  const int MA = BM / 64;            // A sub-blocks of 64 rows (2 or 1)
  const int ACH = BM * 32;           // ushorts per A 32-k chunk
  const int r_a = tid >> 2;
  const int c8 = ((((tid & 3) - (tid >> 3)) & 3)) << 3;
  const unsigned short* arow0; const unsigned short* arow1 = nullptr;
  if (EXPERT && MODE == 0) {
    int t0 = token_list[row0 + r_a];       if (t0 < 0) t0 = 0;
    arow0 = A + (size_t)t0 * lda + c8;
    if (MA == 2) {
      int t1 = token_list[row0 + r_a + 64];  if (t1 < 0) t1 = 0;
      arow1 = A + (size_t)t1 * lda + c8;
    }
  } else {
    arow0 = A + (size_t)(row0 + r_a) * lda + c8;
    if (MA == 2) arow1 = A + (size_t)(row0 + r_a + 64) * lda + c8;
  }
  const unsigned short* brow0 = Bt + (size_t)r_a * K + c8;
  const unsigned short* brow1 = Bt + (size_t)(r_a + 64) * K + c8;

  const int lane = tid & 63, wid = tid >> 6;
  const int wm = wid & 1, wn = wid >> 1;
  const int l15 = lane & 15, qd = lane >> 4;
  const int WR = BM / 2;             // rows per wave-m
  const int NA = WR / 16;            // a-tiles per wave

  char* asb0 = (char*)As + wid * 1024;
  char* asb1 = (char*)As + (ACH / 2) * 2 + wid * 1024;      // rows 64..127 of chunk0 (BM=128 only)
  char* bsb0 = (char*)Bs + wid * 1024;
  char* bsb1 = (char*)Bs + 4096 + wid * 1024;

  f32x4 acc[NA][4] = {};
  const int rdsw = ((qd + (l15 >> 1)) & 3) * 8;
  const bf16x8* afp = (const bf16x8*)&As[(wm * WR + l15) * 32 + rdsw];
  const bf16x8* bfp = (const bf16x8*)&Bs[(wn * 64 + l15) * 32 + rdsw];

  for (int k0 = 0; k0 < K; k0 += 64) {
    __syncthreads();
    // chunk 0 (k0..k0+31)
    async16(asb0, arow0 + k0);
    if (MA == 2) async16(asb1, arow1 + k0);
    async16(bsb0, brow0 + k0);
    async16(bsb1, brow1 + k0);
    // chunk 1 (k0+32..k0+63)
    async16(asb0 + ACH * 2, arow0 + k0 + 32);
    if (MA == 2) async16(asb1 + ACH * 2, arow1 + k0 + 32);
    async16(bsb0 + 8192, brow0 + k0 + 32);
    async16(bsb1 + 8192, brow1 + k0 + 32);
    __syncthreads();
#pragma unroll
    for (int ch = 0; ch < 2; ++ch) {
      const bf16x8* afc = (const bf16x8*)((const char*)afp + ch * ACH * 2);
      const bf16x8* bfc = (const bf16x8*)((const char*)bfp + ch * 8192);
      bf16x8 af[NA], bq[4];
#pragma unroll
      for (int a = 0; a < NA; ++a) af[a] = afc[a * 64];
#pragma unroll
      for (int b2 = 0; b2 < 4; ++b2) bq[b2] = bfc[b2 * 64];
#pragma unroll
      for (int a = 0; a < NA; ++a)
#pragma unroll
        for (int b2 = 0; b2 < 4; ++b2)
          acc[a][b2] = __builtin_amdgcn_mfma_f32_16x16x32_bf16(af[a], bq[b2], acc[a][b2], 0, 0, 0);
    }
  }

  const int mloc = wm * WR + qd * 4;
  const int nloc = wn * 64 + l15;
#pragma unroll
  for (int b2 = 0; b2 < 4; ++b2) {
    const int n = bn * 128 + nloc + b2 * 16;
    const float bv = bp[nloc + b2 * 16];
#pragma unroll
    for (int a = 0; a < NA; ++a) {
#pragma unroll
      for (int r = 0; r < 4; ++r) {
        const int m = mloc + a * 16 + r;
        const float val = acc[a][b2][r] + bv;
        if (MODE == 0) {
          const float sg = val / (1.f + __expf(-val));
          outA[(size_t)(row0 + m) * N + n] = f2b(sg);
        } else if (MODE == 1) {
          outA[(size_t)(row0 + m) * N + n] = f2b(val);
        } else if (MODE == 2) {
          outp[(size_t)(row0 + m) * DIM + n] = 0.25f * val;
        } else {
          const size_t o = (size_t)(row0 + m) * DIM + n;
          outp[o] = xres[o] + mix[o] + val;
        }
      }
    }
  }
}

// ---- fused pair 1: expert GEMM1 (1280 blocks) + shared GEMM1 (256 blocks), BM=128 ----
// bn is slowest-varying -> consecutive blocks share the B weight strip (L2 locality)
__global__ __launch_bounds__(256) void gemm_g1(
    const unsigned short* __restrict__ hb,
    const unsigned short* __restrict__ ew1T, const float* __restrict__ eb1,
    const unsigned short* __restrict__ sw1T, const float* __restrict__ sb1,
    const int* __restrict__ tiledesc, const int* __restrict__ token_list,
    unsigned short* __restrict__ Abuf, unsigned short* __restrict__ Sbuf) {
  __shared__ unsigned short As[128 * 64];
  __shared__ unsigned short Bs[128 * 64];
  const int id = blockIdx.x;
  if (id < MAXTILES * 16) {
    const int bn = id / MAXTILES, by = id % MAXTILES;
    const int expert = tiledesc[by * 2];
    if (expert < 0) return;
    const int row0 = tiledesc[by * 2 + 1];
    gemm_body<0, true, 128>(hb, DIM, ew1T, eb1, DIM, DHID, row0, expert, bn,
                            token_list, Abuf, nullptr, nullptr, nullptr, As, Bs);
  } else {
    const int id2 = id - MAXTILES * 16;
    const int bn = id2 >> 5, by = id2 & 31;
    gemm_body<0, false, 128>(hb, DIM, sw1T, sb1, DIM, DSH, by * 128, 0, bn,
                             nullptr, Sbuf, nullptr, nullptr, nullptr, As, Bs);
  }
}

// ---- fused pair 2: expert GEMM2 (640 blocks) + shared GEMM2 (256 blocks), BM=64 ----
__global__ __launch_bounds__(256) void gemm_g2(
    const unsigned short* __restrict__ Abuf,
    const unsigned short* __restrict__ ew2T, const float* __restrict__ eb2,
    const unsigned short* __restrict__ Sbuf,
    const unsigned short* __restrict__ sw2T, const float* __restrict__ sb2,
    const int* __restrict__ tiledesc,
    unsigned short* __restrict__ eyb, float* __restrict__ shb) {
  __shared__ unsigned short As[64 * 64];
  __shared__ unsigned short Bs[128 * 64];
  const int id = blockIdx.x;
  if (id < MAXTILES * 8) {
    const int bn = id / (MAXTILES * 2), rest = id % (MAXTILES * 2);
    const int seg = rest >> 1, sub = rest & 1;
    const int expert = tiledesc[seg * 2];
    if (expert < 0) return;
    const int row0 = tiledesc[seg * 2 + 1] + sub * 64;
    gemm_body<1, true, 64>(Abuf, DHID, ew2T, eb2, DHID, DIM, row0, expert, bn,
                           nullptr, eyb, nullptr, nullptr, nullptr, As, Bs);
  } else {
    const int id2 = id - MAXTILES * 8;
    const int bn = id2 >> 6, by = id2 & 63;
    gemm_body<2, false, 64>(Sbuf, DSH, sw2T, sb2, DSH, DIM, by * 64, 0, bn,
                            nullptr, nullptr, nullptr, nullptr, shb, As, Bs);
  }
}

// ---- standalone GEMMs for the final ff block (by fast, bn slow) ----
__global__ __launch_bounds__(256) void gemm_ff1(
    const unsigned short* __restrict__ A,
    const unsigned short* __restrict__ BT, const float* __restrict__ bias,
    unsigned short* __restrict__ outA) {
  __shared__ unsigned short As[128 * 64];
  __shared__ unsigned short Bs[128 * 64];
  gemm_body<0, false, 128>(A, DIM, BT, bias, DIM, DHID, blockIdx.x * 128, 0, blockIdx.y,
                           nullptr, outA, nullptr, nullptr, nullptr, As, Bs);
}
__global__ __launch_bounds__(256) void gemm_ff2(
    const unsigned short* __restrict__ A,
    const unsigned short* __restrict__ BT, const float* __restrict__ bias,
    const float* __restrict__ mix, const float* __restrict__ xres,
    float* __restrict__ outp) {
  __shared__ unsigned short As[64 * 64];
  __shared__ unsigned short Bs[128 * 64];
  gemm_body<3, false, 64>(A, DHID, BT, bias, DHID, DIM, blockIdx.x * 64, 0, blockIdx.y,
                          nullptr, nullptr, mix, xres, outp, As, Bs);
}

extern "C" void kernel_launch(void* const* d_in, const int* in_sizes, int n_in,
                              void* d_out, int out_size, void* d_ws, size_t ws_size,
                              hipStream_t stream) {
  (void)in_sizes; (void)n_in; (void)out_size; (void)ws_size;
  const float* x    = (const float*)d_in[0];
  const float* lng  = (const float*)d_in[1];
  const float* lnb  = (const float*)d_in[2];
  const float* rw   = (const float*)d_in[3];
  const float* rb   = (const float*)d_in[4];
  const float* ew1  = (const float*)d_in[5];
  const float* eb1  = (const float*)d_in[6];
  const float* ew2  = (const float*)d_in[7];
  const float* eb2  = (const float*)d_in[8];
  const float* sw1  = (const float*)d_in[9];
  const float* sb1  = (const float*)d_in[10];
  const float* sw2  = (const float*)d_in[11];
  const float* sb2  = (const float*)d_in[12];
  const float* flng = (const float*)d_in[13];
  const float* flnb = (const float*)d_in[14];
  const float* fw1  = (const float*)d_in[15];
  const float* fb1  = (const float*)d_in[16];
  const float* fw2  = (const float*)d_in[17];
  const float* fb2  = (const float*)d_in[18];
  float* out = (float*)d_out;

  char* ws = (char*)d_ws;
  size_t off = 0;
  auto alloc = [&](size_t bytes) -> void* {
    void* p = ws + off;
    off += (bytes + 255) & ~(size_t)255;
    return p;
  };
  unsigned short* ew1T = (unsigned short*)alloc((size_t)NEXP * DIM * DHID * 2);
  unsigned short* ew2T = (unsigned short*)alloc((size_t)NEXP * DHID * DIM * 2);
  unsigned short* sw1T = (unsigned short*)alloc((size_t)DIM * DSH * 2);
  unsigned short* sw2T = (unsigned short*)alloc((size_t)DSH * DIM * 2);
  unsigned short* fw1T = (unsigned short*)alloc((size_t)DIM * DHID * 2);
  unsigned short* fw2T = (unsigned short*)alloc((size_t)DHID * DIM * 2);
  unsigned short* hb   = (unsigned short*)alloc((size_t)T_TOK * DIM * 2);
  unsigned short* fhb  = (unsigned short*)alloc((size_t)T_TOK * DIM * 2);
  unsigned short* Abuf = (unsigned short*)alloc((size_t)ROWSCAP * DHID * 2);
  unsigned short* Sbuf = (unsigned short*)alloc((size_t)T_TOK * DSH * 2);
  unsigned short* eyb  = (unsigned short*)alloc((size_t)ROWSCAP * DIM * 2);
  float* shb = (float*)alloc((size_t)T_TOK * DIM * 4);
  float* moe = (float*)alloc((size_t)T_TOK * DIM * 4);
  int*   comb_idx = (int*)alloc((size_t)T_TOK * 2 * 4);
  float* comb_w   = (float*)alloc((size_t)T_TOK * 2 * 4);
  int*   slots    = (int*)alloc((size_t)T_TOK * 2 * 4);
  int* counts   = (int*)alloc(64);
  int* offs     = (int*)alloc(64);
  int* fill     = (int*)alloc(64);
  int* tiledesc = (int*)alloc(MAXTILES * 2 * 4);
  int* token_list = (int*)alloc((size_t)ROWSCAP * 4);

  hipMemsetAsync(counts, 0, 64, stream);
  hipMemsetAsync(token_list, 0xFF, (size_t)ROWSCAP * 4, stream);  // -1

  prep_kernel<<<9984, 256, 0, stream>>>(x, lng, lnb, rw, rb, hb, comb_idx, comb_w, counts,
                                        ew1, ew2, sw1, sw2, fw1, fw2,
                                        ew1T, ew2T, sw1T, sw2T, fw1T, fw2T);
  plan_kernel<<<1, 64, 0, stream>>>(counts, offs, fill, tiledesc);
  scatter_kernel<<<T_TOK / 256, 256, 0, stream>>>(comb_idx, comb_w, offs, fill, token_list, slots);

  gemm_g1<<<MAXTILES * 16 + 256, 256, 0, stream>>>(hb, ew1T, eb1, sw1T, sb1,
                                                   tiledesc, token_list, Abuf, Sbuf);
  gemm_g2<<<MAXTILES * 8 + 256, 256, 0, stream>>>(Abuf, ew2T, eb2, Sbuf, sw2T, sb2,
                                                  tiledesc, eyb, shb);
  combine_ln_kernel<<<T_TOK / 4, 256, 0, stream>>>(eyb, shb, slots, comb_w, flng, flnb, moe, fhb);
  gemm_ff1<<<dim3(T_TOK / 128, DHID / 128), 256, 0, stream>>>(fhb, fw1T, fb1, Abuf);
  gemm_ff2<<<dim3(T_TOK / 64, DIM / 128), 256, 0, stream>>>(Abuf, fw2T, fb2, moe, x, out);
}

// Round 7
// 386.562 us; speedup vs baseline: 1.0586x; 1.0586x over previous
//
#include <hip/hip_runtime.h>
#include <stdint.h>

// Problem constants
#define T_TOK 4096   // B*S
#define DIM   512    // D
#define NEXP  16     // E
#define DHID  2048   // 4*D
#define DSH   1024   // 2*D
#define ROWSCAP 10240  // 2*T + padding slack
#define MAXTILES 80    // sum ceil(c_e/128) <= 79

typedef __bf16 bf16x8 __attribute__((ext_vector_type(8)));
typedef float  f32x4  __attribute__((ext_vector_type(4)));
typedef unsigned short usv8 __attribute__((ext_vector_type(8)));

__device__ __forceinline__ unsigned short f2b(float f) {
  union { float f; unsigned int u; } un; un.f = f;
  unsigned int u = un.u + 0x7fffu + ((un.u >> 16) & 1u);  // RNE to bf16
  return (unsigned short)(u >> 16);
}
__device__ __forceinline__ float b2f(unsigned short u) {
  union { unsigned int u; float f; } un; un.u = ((unsigned int)u) << 16; return un.f;
}

__device__ __forceinline__ void async16(void* lds, const void* gp) {
  __builtin_amdgcn_global_load_lds(
      (const __attribute__((address_space(1))) unsigned int*)gp,
      (__attribute__((address_space(3))) unsigned int*)lds, 16, 0, 0);
}

// ---------------- 64x64 transpose tile: fp32 [R,C] -> bf16 [C,R] ----------------
// LDS: float row-major [64][65] (65 = 1 mod 32 -> all scalar accesses 2-way = free).
__device__ __forceinline__ void transpose64(
    const float* __restrict__ s, unsigned short* __restrict__ d, int R, int C,
    int tx, int ty, float* tile) {
  const int tid = threadIdx.x;
  const int c0 = tx * 64, r0 = ty * 64;
  const int r = tid >> 4, j4 = (tid & 15) * 4;
#pragma unroll
  for (int p = 0; p < 4; ++p) {
    const int row = r + p * 16;
    const float4 v = *(const float4*)&s[(size_t)(r0 + row) * C + c0 + j4];
    tile[row * 65 + j4 + 0] = v.x;
    tile[row * 65 + j4 + 1] = v.y;
    tile[row * 65 + j4 + 2] = v.z;
    tile[row * 65 + j4 + 3] = v.w;
  }
  __syncthreads();
  const int jj = tid & 7, cc = tid >> 3;
#pragma unroll
  for (int p = 0; p < 2; ++p) {
    const int c = cc + p * 32;
    usv8 u;
#pragma unroll
    for (int i = 0; i < 8; ++i) u[i] = f2b(tile[(jj * 8 + i) * 65 + c]);
    *(usv8*)&d[(size_t)(c0 + c) * R + r0 + jj * 8] = u;
  }
}

// ---------------- prep: ew1+sw1 transposes + LN+router+top2 ----------------
// (ew2/sw2/fw1/fw2 transposes are fused into gemm_g1 - they're not needed until g2/ff)
__global__ __launch_bounds__(256) void prep_kernel(
    const float* __restrict__ x, const float* __restrict__ g, const float* __restrict__ b,
    const float* __restrict__ rw, const float* __restrict__ rb,
    unsigned short* __restrict__ hbuf, int* __restrict__ comb_idx, float* __restrict__ comb_w,
    int* __restrict__ counts,
    const float* __restrict__ ew1, const float* __restrict__ sw1,
    unsigned short* __restrict__ ew1T, unsigned short* __restrict__ sw1T) {
  __shared__ float tile[64 * 65];
  __shared__ int hist[NEXP];
  const int id = blockIdx.x;
  if (id >= 1024) {
    int id2 = id - 1024;
    const float* s; unsigned short* d; int R, C, t, tx, ty;
    if (id2 < 4096)      { int bm = id2 >> 8; t = id2 & 255; R = 512;  C = 2048;
                           s = ew1 + (size_t)bm * R * C; d = ew1T + (size_t)bm * R * C;
                           tx = t & 31; ty = t >> 5; }
    else                 { t = id2 - 4096; R = 512;  C = 1024; s = sw1; d = sw1T; tx = t & 15; ty = t >> 4; }
    transpose64(s, d, R, C, tx, ty, tile);
    return;
  }
  // ---- LN + router path (wave-per-token) ----
  const int wid = threadIdx.x >> 6, lane = threadIdx.x & 63;
  const int t = id * 4 + wid;
  if (threadIdx.x < NEXP) hist[threadIdx.x] = 0;
  __syncthreads();

  const float4* xr = (const float4*)(x + (size_t)t * DIM);
  const float4 va = xr[lane], vb = xr[lane + 64];
  float s = (va.x + va.y) + (va.z + va.w) + ((vb.x + vb.y) + (vb.z + vb.w));
#pragma unroll
  for (int o = 32; o; o >>= 1) s += __shfl_xor(s, o, 64);
  const float mu = s * (1.f / DIM);
  float da[4] = {va.x - mu, va.y - mu, va.z - mu, va.w - mu};
  float db[4] = {vb.x - mu, vb.y - mu, vb.z - mu, vb.w - mu};
  float q = (da[0]*da[0] + da[1]*da[1]) + (da[2]*da[2] + da[3]*da[3]) +
            ((db[0]*db[0] + db[1]*db[1]) + (db[2]*db[2] + db[3]*db[3]));
#pragma unroll
  for (int o = 32; o; o >>= 1) q += __shfl_xor(q, o, 64);
  const float rs = rsqrtf(q * (1.f / DIM) + 1e-5f);
  const float4 ga = ((const float4*)g)[lane], gb4 = ((const float4*)g)[lane + 64];
  const float4 ba = ((const float4*)b)[lane], bb4 = ((const float4*)b)[lane + 64];
  float ha[4], hbv[4];
  ha[0] = da[0] * rs * ga.x + ba.x;  ha[1] = da[1] * rs * ga.y + ba.y;
  ha[2] = da[2] * rs * ga.z + ba.z;  ha[3] = da[3] * rs * ga.w + ba.w;
  hbv[0] = db[0] * rs * gb4.x + bb4.x;  hbv[1] = db[1] * rs * gb4.y + bb4.y;
  hbv[2] = db[2] * rs * gb4.z + bb4.z;  hbv[3] = db[3] * rs * gb4.w + bb4.w;
  ushort4 ua = {f2b(ha[0]), f2b(ha[1]), f2b(ha[2]), f2b(ha[3])};
  ushort4 ub = {f2b(hbv[0]), f2b(hbv[1]), f2b(hbv[2]), f2b(hbv[3])};
  ((ushort4*)(hbuf + (size_t)t * DIM))[lane] = ua;
  ((ushort4*)(hbuf + (size_t)t * DIM))[lane + 64] = ub;

  float p[NEXP];
#pragma unroll
  for (int e = 0; e < NEXP; ++e) p[e] = 0.f;
  const int col0 = lane * 4;
#pragma unroll
  for (int half = 0; half < 2; ++half) {
#pragma unroll
    for (int j = 0; j < 4; ++j) {
      const int col = half * 256 + col0 + j;
      const float hv = half ? hbv[j] : ha[j];
      const float4* wr = (const float4*)(rw + (size_t)col * NEXP);
#pragma unroll
      for (int qq = 0; qq < 4; ++qq) {
        const float4 w = wr[qq];
        p[qq * 4 + 0] += hv * w.x;  p[qq * 4 + 1] += hv * w.y;
        p[qq * 4 + 2] += hv * w.z;  p[qq * 4 + 3] += hv * w.w;
      }
    }
  }
#pragma unroll
  for (int o = 32; o; o >>= 1) {
#pragma unroll
    for (int e = 0; e < NEXP; ++e) p[e] += __shfl_xor(p[e], o, 64);
  }
  float mx = -1e30f;
#pragma unroll
  for (int e = 0; e < NEXP; ++e) {
    p[e] = (p[e] + rb[e]) * (1.f / 0.7f);
    mx = fmaxf(mx, p[e]);
  }
  float ge[NEXP], se = 0.f;
#pragma unroll
  for (int e = 0; e < NEXP; ++e) { ge[e] = __expf(p[e] - mx); se += ge[e]; }
  const float inv = 1.f / se;
  int i0 = 0; float m0 = ge[0];
#pragma unroll
  for (int e = 1; e < NEXP; ++e) if (ge[e] > m0) { m0 = ge[e]; i0 = e; }
  int i1 = -1; float m1 = -1.f;
#pragma unroll
  for (int e = 0; e < NEXP; ++e) if (e != i0 && ge[e] > m1) { m1 = ge[e]; i1 = e; }
  if (lane == 0) {
    comb_idx[t * 2] = i0; comb_idx[t * 2 + 1] = i1;
    comb_w[t * 2] = m0 * inv; comb_w[t * 2 + 1] = m1 * inv;
    atomicAdd(&hist[i0], 1); atomicAdd(&hist[i1], 1);
  }
  __syncthreads();
  if (threadIdx.x < NEXP) {
    const int c = hist[threadIdx.x];
    if (c) atomicAdd(&counts[threadIdx.x], c);
  }
}

// ---------------- plan: padded segment offsets + tile descriptors ----------------
__global__ void plan_kernel(const int* __restrict__ counts, int* __restrict__ offs,
                            int* __restrict__ fill, int* __restrict__ tiledesc) {
  if (threadIdx.x == 0) {
    int run = 0, tix = 0;
    for (int e = 0; e < NEXP; ++e) {
      offs[e] = run;
      const int nt = (counts[e] + 127) >> 7;
      for (int i = 0; i < nt; ++i) { tiledesc[tix * 2] = e; tiledesc[tix * 2 + 1] = run + i * 128; ++tix; }
      run += nt * 128;
    }
    for (; tix < MAXTILES; ++tix) { tiledesc[tix * 2] = -1; tiledesc[tix * 2 + 1] = 0; }
  }
  if (threadIdx.x < NEXP) fill[threadIdx.x] = 0;
}

// ---------------- scatter: block-local histogram + rank, 16 global atomics/block ----------------
__global__ __launch_bounds__(256) void scatter_kernel(
    const int* __restrict__ comb_idx, const int* __restrict__ offs, int* __restrict__ fill,
    int* __restrict__ token_list, int* __restrict__ slots) {
  __shared__ int hist[NEXP], base[NEXP];
  if (threadIdx.x < NEXP) hist[threadIdx.x] = 0;
  __syncthreads();
  const int t = blockIdx.x * 256 + threadIdx.x;
  const int e0 = comb_idx[t * 2], e1 = comb_idx[t * 2 + 1];
  const int r0 = atomicAdd(&hist[e0], 1);
  const int r1 = atomicAdd(&hist[e1], 1);
  __syncthreads();
  if (threadIdx.x < NEXP) base[threadIdx.x] = atomicAdd(&fill[threadIdx.x], hist[threadIdx.x]);
  __syncthreads();
  const int g0 = offs[e0] + base[e0] + r0;
  const int g1 = offs[e1] + base[e1] + r1;
  token_list[g0] = t; token_list[g1] = t;
  slots[t * 2] = g0; slots[t * 2 + 1] = g1;
}

// ---------------- combine + LayerNorm ----------------
__global__ __launch_bounds__(256) void combine_ln_kernel(
    const unsigned short* __restrict__ eyb, const float* __restrict__ shb,
    const int* __restrict__ slots, const float* __restrict__ comb_w,
    const float* __restrict__ g, const float* __restrict__ b,
    float* __restrict__ moe, unsigned short* __restrict__ fhb) {
  const int wid = threadIdx.x >> 6, lane = threadIdx.x & 63;
  const int t = blockIdx.x * 4 + wid;
  const int s0 = slots[t * 2], s1 = slots[t * 2 + 1];
  const float w0 = comb_w[t * 2], w1 = comb_w[t * 2 + 1];
  const uint4 E0 = ((const uint4*)(eyb + (size_t)s0 * DIM))[lane];
  const uint4 E1 = ((const uint4*)(eyb + (size_t)s1 * DIM))[lane];
  const float4 sa = ((const float4*)(shb + (size_t)t * DIM))[lane * 2];
  const float4 sb = ((const float4*)(shb + (size_t)t * DIM))[lane * 2 + 1];
  const unsigned int e0[4] = {E0.x, E0.y, E0.z, E0.w};
  const unsigned int e1[4] = {E1.x, E1.y, E1.z, E1.w};
  const float shv[8] = {sa.x, sa.y, sa.z, sa.w, sb.x, sb.y, sb.z, sb.w};
  float m[8];
#pragma unroll
  for (int j = 0; j < 4; ++j) {
    m[2*j]   = w0 * b2f((unsigned short)(e0[j] & 0xffff)) + w1 * b2f((unsigned short)(e1[j] & 0xffff)) + shv[2*j];
    m[2*j+1] = w0 * b2f((unsigned short)(e0[j] >> 16))    + w1 * b2f((unsigned short)(e1[j] >> 16))    + shv[2*j+1];
  }
  float4* mo = (float4*)(moe + (size_t)t * DIM);
  mo[lane * 2]     = make_float4(m[0], m[1], m[2], m[3]);
  mo[lane * 2 + 1] = make_float4(m[4], m[5], m[6], m[7]);
  float s = 0.f;
#pragma unroll
  for (int j = 0; j < 8; ++j) s += m[j];
#pragma unroll
  for (int o = 32; o; o >>= 1) s += __shfl_xor(s, o, 64);
  const float mu = s * (1.f / DIM);
  float q = 0.f;
#pragma unroll
  for (int j = 0; j < 8; ++j) { const float d = m[j] - mu; q += d * d; }
#pragma unroll
  for (int o = 32; o; o >>= 1) q += __shfl_xor(q, o, 64);
  const float rs = rsqrtf(q * (1.f / DIM) + 1e-5f);
  const float4 ga = ((const float4*)g)[lane * 2], gb4 = ((const float4*)g)[lane * 2 + 1];
  const float4 ba = ((const float4*)b)[lane * 2], bb4 = ((const float4*)b)[lane * 2 + 1];
  const float gv[8] = {ga.x, ga.y, ga.z, ga.w, gb4.x, gb4.y, gb4.z, gb4.w};
  const float bv[8] = {ba.x, ba.y, ba.z, ba.w, bb4.x, bb4.y, bb4.z, bb4.w};
  ushort4 o0, o1;
  o0.x = f2b((m[0]-mu)*rs*gv[0]+bv[0]); o0.y = f2b((m[1]-mu)*rs*gv[1]+bv[1]);
  o0.z = f2b((m[2]-mu)*rs*gv[2]+bv[2]); o0.w = f2b((m[3]-mu)*rs*gv[3]+bv[3]);
  o1.x = f2b((m[4]-mu)*rs*gv[4]+bv[4]); o1.y = f2b((m[5]-mu)*rs*gv[5]+bv[5]);
  o1.z = f2b((m[6]-mu)*rs*gv[6]+bv[6]); o1.w = f2b((m[7]-mu)*rs*gv[7]+bv[7]);
  ((ushort4*)(fhb + (size_t)t * DIM))[lane * 2]     = o0;
  ((ushort4*)(fhb + (size_t)t * DIM))[lane * 2 + 1] = o1;
}

// ---------------- bf16 MFMA GEMM body, BMx128x32 tile (BK=32, 16KB LDS: reverted) ----------------
// MODE 0: outA = silu(acc+bias) bf16 | MODE 1: outA = acc+bias bf16
// MODE 2: outp = 0.25*(acc+bias) fp32 | MODE 3: outp = xres + mix + (acc+bias)
template <int MODE, bool EXPERT, int BM>
__device__ __forceinline__ void gemm_body(
    const unsigned short* __restrict__ A, int lda,
    const unsigned short* __restrict__ BT, const float* __restrict__ bias,
    int K, int N, int row0, int expert, int bn,
    const int* __restrict__ token_list,
    unsigned short* __restrict__ outA, const float* __restrict__ mix,
    const float* __restrict__ xres, float* __restrict__ outp,
    unsigned short* As, unsigned short* Bs) {
  const int tid = threadIdx.x;
  const unsigned short* Bt = BT + (size_t)expert * N * K + (size_t)bn * 128 * K;
  const float* bp = bias + (EXPERT ? expert * N : 0) + bn * 128;

  const int MA = BM / 64;            // A sub-blocks of 64 rows (2 or 1)
  const int r_a = tid >> 2;
  const int c8 = ((((tid & 3) - (tid >> 3)) & 3)) << 3;
  const unsigned short* arow0; const unsigned short* arow1 = nullptr;
  if (EXPERT && MODE == 0) {
    int t0 = token_list[row0 + r_a];       if (t0 < 0) t0 = 0;
    arow0 = A + (size_t)t0 * lda + c8;
    if (MA == 2) {
      int t1 = token_list[row0 + r_a + 64];  if (t1 < 0) t1 = 0;
      arow1 = A + (size_t)t1 * lda + c8;
    }
  } else {
    arow0 = A + (size_t)(row0 + r_a) * lda + c8;
    if (MA == 2) arow1 = A + (size_t)(row0 + r_a + 64) * lda + c8;
  }
  const unsigned short* brow0 = Bt + (size_t)r_a * K + c8;
  const unsigned short* brow1 = Bt + (size_t)(r_a + 64) * K + c8;

  const int lane = tid & 63, wid = tid >> 6;
  const int wm = wid & 1, wn = wid >> 1;
  const int l15 = lane & 15, qd = lane >> 4;
  const int WR = BM / 2;             // rows per wave-m
  const int NA = WR / 16;            // a-tiles per wave

  char* asb0 = (char*)As + wid * 1024;
  char* asb1 = (char*)As + 4096 + wid * 1024;   // only used when MA==2
  char* bsb0 = (char*)Bs + wid * 1024;
  char* bsb1 = (char*)Bs + 4096 + wid * 1024;

  f32x4 acc[NA][4] = {};
  const int rdsw = ((qd + (l15 >> 1)) & 3) * 8;
  const bf16x8* afp = (const bf16x8*)&As[(wm * WR + l15) * 32 + rdsw];
  const bf16x8* bfp = (const bf16x8*)&Bs[(wn * 64 + l15) * 32 + rdsw];

  for (int k0 = 0; k0 < K; k0 += 32) {
    __syncthreads();
    async16(asb0, arow0 + k0);
    if (MA == 2) async16(asb1, arow1 + k0);
    async16(bsb0, brow0 + k0);
    async16(bsb1, brow1 + k0);
    __syncthreads();
    bf16x8 af[NA], bq[4];
#pragma unroll
    for (int a = 0; a < NA; ++a) af[a] = afp[a * 64];
#pragma unroll
    for (int b2 = 0; b2 < 4; ++b2) bq[b2] = bfp[b2 * 64];
#pragma unroll
    for (int a = 0; a < NA; ++a)
#pragma unroll
      for (int b2 = 0; b2 < 4; ++b2)
        acc[a][b2] = __builtin_amdgcn_mfma_f32_16x16x32_bf16(af[a], bq[b2], acc[a][b2], 0, 0, 0);
  }

  const int mloc = wm * WR + qd * 4;
  const int nloc = wn * 64 + l15;
#pragma unroll
  for (int b2 = 0; b2 < 4; ++b2) {
    const int n = bn * 128 + nloc + b2 * 16;
    const float bv = bp[nloc + b2 * 16];
#pragma unroll
    for (int a = 0; a < NA; ++a) {
#pragma unroll
      for (int r = 0; r < 4; ++r) {
        const int m = mloc + a * 16 + r;
        const float val = acc[a][b2][r] + bv;
        if (MODE == 0) {
          const float sg = val / (1.f + __expf(-val));
          outA[(size_t)(row0 + m) * N + n] = f2b(sg);
        } else if (MODE == 1) {
          outA[(size_t)(row0 + m) * N + n] = f2b(val);
        } else if (MODE == 2) {
          outp[(size_t)(row0 + m) * DIM + n] = 0.25f * val;
        } else {
          const size_t o = (size_t)(row0 + m) * DIM + n;
          outp[o] = xres[o] + mix[o] + val;
        }
      }
    }
  }
}

// ---- g1: expert GEMM1 (1280) + shared GEMM1 (256) + ew2/sw2/fw1/fw2 transposes (4736) ----
// bn slowest-varying -> concurrent blocks share one B strip (L2 locality).
// Transpose blocks are BW/VALU-only and co-schedule with the MFMA-heavy GEMM blocks.
__global__ __launch_bounds__(256) void gemm_g1(
    const unsigned short* __restrict__ hb,
    const unsigned short* __restrict__ ew1T, const float* __restrict__ eb1,
    const unsigned short* __restrict__ sw1T, const float* __restrict__ sb1,
    const int* __restrict__ tiledesc, const int* __restrict__ token_list,
    unsigned short* __restrict__ Abuf, unsigned short* __restrict__ Sbuf,
    const float* __restrict__ ew2, const float* __restrict__ sw2,
    const float* __restrict__ fw1, const float* __restrict__ fw2,
    unsigned short* __restrict__ ew2T, unsigned short* __restrict__ sw2T,
    unsigned short* __restrict__ fw1T, unsigned short* __restrict__ fw2T) {
  __shared__ char smem[16640];  // max(GEMM 16KB, transpose tile 16.64KB)
  unsigned short* As = (unsigned short*)smem;
  unsigned short* Bs = (unsigned short*)(smem + 8192);
  const int id = blockIdx.x;
  if (id < MAXTILES * 16) {
    const int bn = id / MAXTILES, by = id % MAXTILES;
    const int expert = tiledesc[by * 2];
    if (expert < 0) return;
    const int row0 = tiledesc[by * 2 + 1];
    gemm_body<0, true, 128>(hb, DIM, ew1T, eb1, DIM, DHID, row0, expert, bn,
                            token_list, Abuf, nullptr, nullptr, nullptr, As, Bs);
  } else if (id < MAXTILES * 16 + 256) {
    const int id2 = id - MAXTILES * 16;
    const int bn = id2 >> 5, by = id2 & 31;
    gemm_body<0, false, 128>(hb, DIM, sw1T, sb1, DIM, DSH, by * 128, 0, bn,
                             nullptr, Sbuf, nullptr, nullptr, nullptr, As, Bs);
  } else {
    int id2 = id - (MAXTILES * 16 + 256);
    const float* s; unsigned short* d; int R, C, t, tx, ty;
    if (id2 < 4096)      { int bm = id2 >> 8; t = id2 & 255; R = 2048; C = 512;
                           s = ew2 + (size_t)bm * R * C; d = ew2T + (size_t)bm * R * C;
                           tx = t & 7;  ty = t >> 3; }
    else if (id2 < 4224) { t = id2 - 4096; R = 1024; C = 512;  s = sw2; d = sw2T; tx = t & 7;  ty = t >> 3; }
    else if (id2 < 4480) { t = id2 - 4224; R = 512;  C = 2048; s = fw1; d = fw1T; tx = t & 31; ty = t >> 5; }
    else                 { t = id2 - 4480; R = 2048; C = 512;  s = fw2; d = fw2T; tx = t & 7;  ty = t >> 3; }
    transpose64(s, d, R, C, tx, ty, (float*)smem);
  }
}

// ---- g2: expert GEMM2 (640 blocks) + shared GEMM2 (256 blocks), BM=64 ----
__global__ __launch_bounds__(256) void gemm_g2(
    const unsigned short* __restrict__ Abuf,
    const unsigned short* __restrict__ ew2T, const float* __restrict__ eb2,
    const unsigned short* __restrict__ Sbuf,
    const unsigned short* __restrict__ sw2T, const float* __restrict__ sb2,
    const int* __restrict__ tiledesc,
    unsigned short* __restrict__ eyb, float* __restrict__ shb) {
  __shared__ unsigned short As[64 * 32];
  __shared__ unsigned short Bs[128 * 32];
  const int id = blockIdx.x;
  if (id < MAXTILES * 8) {
    const int bn = id / (MAXTILES * 2), rest = id % (MAXTILES * 2);
    const int seg = rest >> 1, sub = rest & 1;
    const int expert = tiledesc[seg * 2];
    if (expert < 0) return;
    const int row0 = tiledesc[seg * 2 + 1] + sub * 64;
    gemm_body<1, true, 64>(Abuf, DHID, ew2T, eb2, DHID, DIM, row0, expert, bn,
                           nullptr, eyb, nullptr, nullptr, nullptr, As, Bs);
  } else {
    const int id2 = id - MAXTILES * 8;
    const int bn = id2 >> 6, by = id2 & 63;
    gemm_body<2, false, 64>(Sbuf, DSH, sw2T, sb2, DSH, DIM, by * 64, 0, bn,
                            nullptr, nullptr, nullptr, nullptr, shb, As, Bs);
  }
}

// ---- standalone GEMMs for the final ff block (by fast, bn slow) ----
__global__ __launch_bounds__(256) void gemm_ff1(
    const unsigned short* __restrict__ A,
    const unsigned short* __restrict__ BT, const float* __restrict__ bias,
    unsigned short* __restrict__ outA) {
  __shared__ unsigned short As[128 * 32];
  __shared__ unsigned short Bs[128 * 32];
  gemm_body<0, false, 128>(A, DIM, BT, bias, DIM, DHID, blockIdx.x * 128, 0, blockIdx.y,
                           nullptr, outA, nullptr, nullptr, nullptr, As, Bs);
}
__global__ __launch_bounds__(256) void gemm_ff2(
    const unsigned short* __restrict__ A,
    const unsigned short* __restrict__ BT, const float* __restrict__ bias,
    const float* __restrict__ mix, const float* __restrict__ xres,
    float* __restrict__ outp) {
  __shared__ unsigned short As[64 * 32];
  __shared__ unsigned short Bs[128 * 32];
  gemm_body<3, false, 64>(A, DHID, BT, bias, DHID, DIM, blockIdx.x * 64, 0, blockIdx.y,
                          nullptr, nullptr, mix, xres, outp, As, Bs);
}

extern "C" void kernel_launch(void* const* d_in, const int* in_sizes, int n_in,
                              void* d_out, int out_size, void* d_ws, size_t ws_size,
                              hipStream_t stream) {
  (void)in_sizes; (void)n_in; (void)out_size; (void)ws_size;
  const float* x    = (const float*)d_in[0];
  const float* lng  = (const float*)d_in[1];
  const float* lnb  = (const float*)d_in[2];
  const float* rw   = (const float*)d_in[3];
  const float* rb   = (const float*)d_in[4];
  const float* ew1  = (const float*)d_in[5];
  const float* eb1  = (const float*)d_in[6];
  const float* ew2  = (const float*)d_in[7];
  const float* eb2  = (const float*)d_in[8];
  const float* sw1  = (const float*)d_in[9];
  const float* sb1  = (const float*)d_in[10];
  const float* sw2  = (const float*)d_in[11];
  const float* sb2  = (const float*)d_in[12];
  const float* flng = (const float*)d_in[13];
  const float* flnb = (const float*)d_in[14];
  const float* fw1  = (const float*)d_in[15];
  const float* fb1  = (const float*)d_in[16];
  const float* fw2  = (const float*)d_in[17];
  const float* fb2  = (const float*)d_in[18];
  float* out = (float*)d_out;

  char* ws = (char*)d_ws;
  size_t off = 0;
  auto alloc = [&](size_t bytes) -> void* {
    void* p = ws + off;
    off += (bytes + 255) & ~(size_t)255;
    return p;
  };
  unsigned short* ew1T = (unsigned short*)alloc((size_t)NEXP * DIM * DHID * 2);
  unsigned short* ew2T = (unsigned short*)alloc((size_t)NEXP * DHID * DIM * 2);
  unsigned short* sw1T = (unsigned short*)alloc((size_t)DIM * DSH * 2);
  unsigned short* sw2T = (unsigned short*)alloc((size_t)DSH * DIM * 2);
  unsigned short* fw1T = (unsigned short*)alloc((size_t)DIM * DHID * 2);
  unsigned short* fw2T = (unsigned short*)alloc((size_t)DHID * DIM * 2);
  unsigned short* hb   = (unsigned short*)alloc((size_t)T_TOK * DIM * 2);
  unsigned short* fhb  = (unsigned short*)alloc((size_t)T_TOK * DIM * 2);
  unsigned short* Abuf = (unsigned short*)alloc((size_t)ROWSCAP * DHID * 2);
  unsigned short* Sbuf = (unsigned short*)alloc((size_t)T_TOK * DSH * 2);
  unsigned short* eyb  = (unsigned short*)alloc((size_t)ROWSCAP * DIM * 2);
  float* shb = (float*)alloc((size_t)T_TOK * DIM * 4);
  float* moe = (float*)alloc((size_t)T_TOK * DIM * 4);
  int*   comb_idx = (int*)alloc((size_t)T_TOK * 2 * 4);
  float* comb_w   = (float*)alloc((size_t)T_TOK * 2 * 4);
  int*   slots    = (int*)alloc((size_t)T_TOK * 2 * 4);
  int* counts   = (int*)alloc(64);
  int* offs     = (int*)alloc(64);
  int* fill     = (int*)alloc(64);
  int* tiledesc = (int*)alloc(MAXTILES * 2 * 4);
  int* token_list = (int*)alloc((size_t)ROWSCAP * 4);

  hipMemsetAsync(counts, 0, 64, stream);
  hipMemsetAsync(token_list, 0xFF, (size_t)ROWSCAP * 4, stream);  // -1

  // ew1+sw1 transposes (4224) + LN/router (1024)
  prep_kernel<<<5248, 256, 0, stream>>>(x, lng, lnb, rw, rb, hb, comb_idx, comb_w, counts,
                                        ew1, sw1, ew1T, sw1T);
  plan_kernel<<<1, 64, 0, stream>>>(counts, offs, fill, tiledesc);
  scatter_kernel<<<T_TOK / 256, 256, 0, stream>>>(comb_idx, offs, fill, token_list, slots);

  // expert G1 + shared G1 + remaining weight transposes (overlapped)
  gemm_g1<<<MAXTILES * 16 + 256 + 4736, 256, 0, stream>>>(
      hb, ew1T, eb1, sw1T, sb1, tiledesc, token_list, Abuf, Sbuf,
      ew2, sw2, fw1, fw2, ew2T, sw2T, fw1T, fw2T);
  gemm_g2<<<MAXTILES * 8 + 256, 256, 0, stream>>>(Abuf, ew2T, eb2, Sbuf, sw2T, sb2,
                                                  tiledesc, eyb, shb);
  combine_ln_kernel<<<T_TOK / 4, 256, 0, stream>>>(eyb, shb, slots, comb_w, flng, flnb, moe, fhb);
  gemm_ff1<<<dim3(T_TOK / 128, DHID / 128), 256, 0, stream>>>(fhb, fw1T, fb1, Abuf);
  gemm_ff2<<<dim3(T_TOK / 64, DIM / 128), 256, 0, stream>>>(Abuf, fw2T, fb2, moe, x, out);
}